// Round 2
// baseline (527.609 us; speedup 1.0000x reference)
//
#include <hip/hip_runtime.h>
#include <hip/hip_bf16.h>

typedef unsigned int u32;

#define BATCH 128
#define NIN   1024
#define DIN   256
#define NC    16
#define DC    32
#define JC    64              // j-rows per k_route block
#define NCHUNK (NIN/JC)       // 16

__device__ __forceinline__ float bflo(u32 v){ return __uint_as_float(v << 16); }
__device__ __forceinline__ float bfhi(u32 v){ return __uint_as_float(v & 0xffff0000u); }
__device__ __forceinline__ u32 bfround(u32 ua){ return (ua + 0x7fffu + ((ua >> 16) & 1u)) >> 16; }
__device__ __forceinline__ u32 pack2(float a, float b){
    return (bfround(__float_as_uint(a)) & 0xffffu) | (bfround(__float_as_uint(b)) << 16);
}

// K1: ysum[b][d] = sum_j x[b][j][d]  (unnormalized iter-0 y; squash is scale-invariant)
__global__ __launch_bounds__(256) void k_colsum(const float* __restrict__ x, float* __restrict__ ysum){
    int chunk = blockIdx.x, b = blockIdx.y, t = threadIdx.x;
    const float* xb = x + ((size_t)b * NIN + chunk * 128) * DIN + t;
    float a = 0.f;
    #pragma unroll 4
    for (int j = 0; j < 128; j++) a += xb[j * DIN];
    atomicAdd(&ysum[b * DIN + t], a);
}

// K2: per (batch, j-chunk): bb[i][j] = x[j,:]·z[i,:]; c = softmax_i(bb); y[i][d] += sum_j c[i][j]*x[j][d]
// x is fp32 in global; converted to bf16 pairs in LDS (internal precision only).
__global__ __launch_bounds__(256) void k_route(const float* __restrict__ x, const float* __restrict__ z,
                                               float* __restrict__ y){
    __shared__ u32   xl[JC * 129];    // 64 rows x 128 words (bf16 pairs), stride 129
    __shared__ float zl[NC * DIN];    // 16 KB
    __shared__ float bbc[NC * JC];    // bb then c, 4 KB
    int b = blockIdx.y, chunk = blockIdx.x, t = threadIdx.x;
    int j0 = chunk * JC;

    // stage z[b] (16x256 f32), coalesced
    #pragma unroll
    for (int m = 0; m < 16; m++) zl[t + 256 * m] = z[(size_t)b * NC * DIN + t + 256 * m];
    // stage x chunk (64x256 fp32 -> bf16 pairs), coalesced float4 loads
    {
        const float4* xg = (const float4*)(x + ((size_t)b * NIN + j0) * DIN);
        #pragma unroll
        for (int k = 0; k < 16; k++){
            int g = t + 256 * k;
            int r = g >> 6, c4 = g & 63;
            float4 v = xg[g];
            int base = r * 129 + c4 * 2;
            xl[base]     = pack2(v.x, v.y);
            xl[base + 1] = pack2(v.z, v.w);
        }
    }
    __syncthreads();

    // bb phase: wave wv handles capsules wv*4..wv*4+3, lane = j
    {
        int j = t & 63, wv = t >> 6, i0 = wv * 4;
        float a0 = 0.f, a1 = 0.f, a2 = 0.f, a3 = 0.f;
        const float2* z0 = (const float2*)&zl[(i0 + 0) * DIN];
        const float2* z1 = (const float2*)&zl[(i0 + 1) * DIN];
        const float2* z2 = (const float2*)&zl[(i0 + 2) * DIN];
        const float2* z3 = (const float2*)&zl[(i0 + 3) * DIN];
        const u32* xr = &xl[j * 129];
        for (int wd = 0; wd < 128; wd++){
            u32 xv = xr[wd];
            float lo = bflo(xv), hi = bfhi(xv);
            float2 q;
            q = z0[wd]; a0 += q.x * lo + q.y * hi;
            q = z1[wd]; a1 += q.x * lo + q.y * hi;
            q = z2[wd]; a2 += q.x * lo + q.y * hi;
            q = z3[wd]; a3 += q.x * lo + q.y * hi;
        }
        bbc[(i0 + 0) * JC + j] = a0;
        bbc[(i0 + 1) * JC + j] = a1;
        bbc[(i0 + 2) * JC + j] = a2;
        bbc[(i0 + 3) * JC + j] = a3;
    }
    __syncthreads();

    // softmax over i (16 capsules) for each j
    if (t < 64){
        float m = -1e30f;
        #pragma unroll
        for (int i = 0; i < NC; i++) m = fmaxf(m, bbc[i * JC + t]);
        float s = 0.f;
        #pragma unroll
        for (int i = 0; i < NC; i++){ float e = __expf(bbc[i * JC + t] - m); bbc[i * JC + t] = e; s += e; }
        float inv = 1.f / s;
        #pragma unroll
        for (int i = 0; i < NC; i++) bbc[i * JC + t] *= inv;
    }
    __syncthreads();

    // y accumulation: thread owns (i, 16 d-pairs); atomicAdd partials into global y
    {
        int i = t >> 4, ts = t & 15;
        float ya[16];
        #pragma unroll
        for (int k = 0; k < 16; k++) ya[k] = 0.f;
        for (int j = 0; j < JC; j++){
            float c = bbc[i * JC + j];
            const u32* xr = &xl[j * 129 + ts];
            #pragma unroll
            for (int k = 0; k < 8; k++){
                u32 xv = xr[16 * k];
                ya[2 * k]     += c * bflo(xv);
                ya[2 * k + 1] += c * bfhi(xv);
            }
        }
        float* yb = y + (size_t)b * NC * DIN + i * DIN;
        #pragma unroll
        for (int k = 0; k < 8; k++){
            int d0 = 2 * (ts + 16 * k);
            atomicAdd(&yb[d0],     ya[2 * k]);
            atomicAdd(&yb[d0 + 1], ya[2 * k + 1]);
        }
    }
}

// K3: y -> s = y@W (col t) -> squash -> o; then z = W@o (unless final: write fp32 out)
__global__ __launch_bounds__(512) void k_out(const float* __restrict__ y, int ybs, int yis,
                                             const float* __restrict__ W, float* __restrict__ z,
                                             float* __restrict__ out, int final){
    __shared__ float yl[NC * DIN];   // 16 KB
    __shared__ float ol[NC * DC];    // 2 KB
    int b = blockIdx.x, t = threadIdx.x;
    #pragma unroll
    for (int m = 0; m < 8; m++){
        int idx = t + 512 * m;
        int i = idx >> 8, d = idx & 255;
        yl[idx] = y[(size_t)b * ybs + i * yis + d];
    }
    __syncthreads();
    // col = t (i = t>>5, k = t&31): s = sum_d y[i][d] * W[d][t]
    int i = t >> 5;
    const float* yr = &yl[i * DIN];
    float s = 0.f;
    for (int d = 0; d < DIN; d++) s += yr[d] * W[d * 512 + t];
    // squash: norm over the 32 cols of capsule i (32-lane half-wave)
    float v = s * s;
    #pragma unroll
    for (int off = 16; off >= 1; off >>= 1) v += __shfl_xor(v, off);
    float o = s / sqrtf(v + 1e-7f);
    if (final){
        out[(size_t)b * NC * DC + t] = o;
        return;
    }
    ol[t] = o;
    __syncthreads();
    // z[i][d] = sum_k W[d][i*32+k] * o[i][k]
    {
        int dsub = t & 31;
        const float* orow = &ol[i * DC];
        #pragma unroll
        for (int m = 0; m < 8; m++){
            int d = dsub + 32 * m;
            const float* wrow = W + d * 512 + i * DC;
            float acc = 0.f;
            #pragma unroll
            for (int kk = 0; kk < 32; kk++) acc += wrow[kk] * orow[kk];
            z[(size_t)b * NC * DIN + i * DIN + d] = acc;
        }
    }
}

extern "C" void kernel_launch(void* const* d_in, const int* in_sizes, int n_in,
                              void* d_out, int out_size, void* d_ws, size_t ws_size,
                              hipStream_t stream){
    const float* x = (const float*)d_in[0];    // fp32 [128][1024][256]
    const float* W = (const float*)d_in[1];    // fp32 [256][512]
    float* out = (float*)d_out;                // fp32 [128][16][32]
    float* f = (float*)d_ws;
    float* ysum = f;                           // 128*256
    float* y    = f + 32768;                   // 128*16*256
    float* z    = f + 32768 + 524288;          // 128*16*256   (ws total ~4.3 MB)

    // iteration 0: c uniform -> y = colsum(x) (scale-invariant); outputs + z
    hipMemsetAsync(ysum, 0, 32768 * sizeof(float), stream);
    k_colsum<<<dim3(8, BATCH), 256, 0, stream>>>(x, ysum);
    k_out<<<BATCH, 512, 0, stream>>>(ysum, DIN, 0, W, z, out, 0);
    // iterations 1..3
    for (int it = 1; it < 4; it++){
        hipMemsetAsync(y, 0, (size_t)BATCH * NC * DIN * sizeof(float), stream);
        k_route<<<dim3(NCHUNK, BATCH), 256, 0, stream>>>(x, z, y);
        k_out<<<BATCH, 512, 0, stream>>>(y, NC * DIN, DIN, W, z, out, it == 3 ? 1 : 0);
    }
}

// Round 3
// 397.458 us; speedup vs baseline: 1.3275x; 1.3275x over previous
//
#include <hip/hip_runtime.h>
#include <hip/hip_bf16.h>

typedef unsigned int u32;
typedef float f32x4 __attribute__((ext_vector_type(4)));
typedef __bf16 bf16x8 __attribute__((ext_vector_type(8)));

#define BATCH 128
#define NIN   1024
#define DIN   256
#define NC    16
#define DC    32
#define JC    64
#define NCHUNK 16

__device__ __forceinline__ u32 bfround(u32 ua){ return (ua + 0x7fffu + ((ua >> 16) & 1u)) >> 16; }
__device__ __forceinline__ u32 pack2(float a, float b){
    return (bfround(__float_as_uint(a)) & 0xffffu) | (bfround(__float_as_uint(b)) << 16);
}
__device__ __forceinline__ bf16x8 ldfrag(const u32* p){
    return __builtin_bit_cast(bf16x8, *(const uint4*)p);
}

// K1: ysum[b][d] = sum_j x[b][j][d]  (unnormalized iter-0 y; squash is scale-invariant)
__global__ __launch_bounds__(256) void k_colsum(const float* __restrict__ x, float* __restrict__ ysum){
    int chunk = blockIdx.x, b = blockIdx.y, t = threadIdx.x;
    const float* xb = x + ((size_t)b * NIN + chunk * 128) * DIN + t;
    float a = 0.f;
    #pragma unroll 4
    for (int j = 0; j < 128; j++) a += xb[j * DIN];
    atomicAdd(&ysum[b * DIN + t], a);
}

// K2: per (batch, j-chunk): bb^T[j][i] = x[j,:]·z[i,:] via MFMA; softmax over i in-register;
//     y[i][d] += sum_j c[i][j] x[j][d] via MFMA (x transposed in LDS). All tiles bf16 in LDS.
__global__ __launch_bounds__(256) void k_route(const float* __restrict__ x, const float* __restrict__ z,
                                               float* __restrict__ y){
    __shared__ __align__(16) u32 xl [64 * 128];   // x tile row-major bf16 pairs, row-swizzled (32 KB)
    __shared__ __align__(16) u32 xtl[256 * 32];   // x tile transposed [d][jpair], swizzled (32 KB)
    __shared__ __align__(16) u32 zl [16 * 128];   // z bf16 pairs row-major, swizzled (8 KB)
    __shared__ __align__(16) u32 cl [16 * 32];    // c bf16 pairs [i][jpair], swizzled (2 KB)
    const int t = threadIdx.x;
    const int bidx = blockIdx.y, chunk = blockIdx.x;
    const int lane = t & 63, wv = t >> 6;
    const int l15 = lane & 15, q = lane >> 4;

    // ---- stage: x chunk 64x256 fp32 -> bf16 pairs; z 16x256 fp32 -> bf16 pairs ----
    {
        const float4* xg = (const float4*)(x + ((size_t)bidx * NIN + chunk * JC) * DIN);
        #pragma unroll
        for (int m = 0; m < 8; m++){
            int p = t + 256 * m;                  // float4-pair index 0..2047
            float4 a = xg[2 * p], c4 = xg[2 * p + 1];
            int j = p >> 5, w = 4 * (p & 31);
            uint4 W4;
            W4.x = pack2(a.x, a.y);  W4.y = pack2(a.z, a.w);
            W4.z = pack2(c4.x, c4.y); W4.w = pack2(c4.z, c4.w);
            *(uint4*)&xl[j * 128 + ((w + 4 * j) & 127)] = W4;
        }
        const float4* zg = (const float4*)(z + (size_t)bidx * NC * DIN);
        #pragma unroll
        for (int m = 0; m < 2; m++){
            int p = t + 256 * m;                  // 0..511
            float4 a = zg[2 * p], c4 = zg[2 * p + 1];
            int i = p >> 5, w = 4 * (p & 31);
            uint4 W4;
            W4.x = pack2(a.x, a.y);  W4.y = pack2(a.z, a.w);
            W4.z = pack2(c4.x, c4.y); W4.w = pack2(c4.z, c4.w);
            *(uint4*)&zl[i * 128 + ((w + 4 * i) & 127)] = W4;
        }
    }
    __syncthreads();

    // ---- GEMM1: bb^T[j][i], wave wv owns j-tile wv*16..+15, K=256 ----
    f32x4 acc1 = {0.f, 0.f, 0.f, 0.f};
    {
        int jr = wv * 16 + l15;                   // A row (m = lane&15)
        #pragma unroll
        for (int ks = 0; ks < 8; ks++){
            int w = ks * 16 + q * 4;
            bf16x8 a = ldfrag(&xl[jr  * 128 + ((w + 4 * jr)  & 127)]);
            bf16x8 b = ldfrag(&zl[l15 * 128 + ((w + 4 * l15) & 127)]);
            acc1 = __builtin_amdgcn_mfma_f32_16x16x32_bf16(a, b, acc1, 0, 0, 0);
        }
    }
    // ---- softmax over i (= lane&15 across the 16 lanes of each quad), per reg (= one j) ----
    float crs[4];
    #pragma unroll
    for (int r = 0; r < 4; r++){
        float v = acc1[r];
        float mx = v;
        mx = fmaxf(mx, __shfl_xor(mx, 1)); mx = fmaxf(mx, __shfl_xor(mx, 2));
        mx = fmaxf(mx, __shfl_xor(mx, 4)); mx = fmaxf(mx, __shfl_xor(mx, 8));
        float e = __expf(v - mx);
        float s = e;
        s += __shfl_xor(s, 1); s += __shfl_xor(s, 2);
        s += __shfl_xor(s, 4); s += __shfl_xor(s, 8);
        crs[r] = e / s;
    }
    // ---- write c to cl[i][jpair] (regs r are consecutive j) ----
    {
        int jp0 = wv * 8 + q * 2;
        uint2 cw; cw.x = pack2(crs[0], crs[1]); cw.y = pack2(crs[2], crs[3]);
        *(uint2*)&cl[l15 * 32 + ((jp0 + 4 * l15) & 31)] = cw;
    }
    // ---- transpose xl -> xtl: thread handles d = 2w, 2w+1; half the jp range ----
    {
        int w = t & 127, jph = (t >> 7) * 16;
        int d0 = 2 * w, d1 = 2 * w + 1;
        #pragma unroll
        for (int g = 0; g < 4; g++){
            u32 o0[4], o1[4];
            #pragma unroll
            for (int e = 0; e < 4; e++){
                int jp = jph + g * 4 + e;
                u32 r0 = xl[(2 * jp)     * 128 + ((w + 8 * jp)     & 127)];
                u32 r1 = xl[(2 * jp + 1) * 128 + ((w + 8 * jp + 4) & 127)];
                o0[e] = (r0 & 0xffffu) | (r1 << 16);
                o1[e] = (r0 >> 16)     | (r1 & 0xffff0000u);
            }
            int jp0 = jph + g * 4;
            *(uint4*)&xtl[d0 * 32 + ((jp0 + 4 * d0) & 31)] = make_uint4(o0[0], o0[1], o0[2], o0[3]);
            *(uint4*)&xtl[d1 * 32 + ((jp0 + 4 * d1) & 31)] = make_uint4(o1[0], o1[1], o1[2], o1[3]);
        }
    }
    __syncthreads();

    // ---- GEMM2: y[i][d] += c[i][j] x[j][d], K=64; wave wv owns d-tiles wv*4..+3 ----
    {
        bf16x8 a0 = ldfrag(&cl[l15 * 32 + ((     q * 4 + 4 * l15) & 31)]);  // ks=0
        bf16x8 a1 = ldfrag(&cl[l15 * 32 + ((16 + q * 4 + 4 * l15) & 31)]);  // ks=1
        float* yb = y + (size_t)bidx * NC * DIN;
        #pragma unroll
        for (int nt = 0; nt < 4; nt++){
            int d = (wv * 4 + nt) * 16 + l15;
            f32x4 acc2 = {0.f, 0.f, 0.f, 0.f};
            bf16x8 b0 = ldfrag(&xtl[d * 32 + ((     q * 4 + 4 * d) & 31)]);
            acc2 = __builtin_amdgcn_mfma_f32_16x16x32_bf16(a0, b0, acc2, 0, 0, 0);
            bf16x8 b1 = ldfrag(&xtl[d * 32 + ((16 + q * 4 + 4 * d) & 31)]);
            acc2 = __builtin_amdgcn_mfma_f32_16x16x32_bf16(a1, b1, acc2, 0, 0, 0);
            #pragma unroll
            for (int r = 0; r < 4; r++)
                atomicAdd(&yb[(q * 4 + r) * DIN + d], acc2[r]);
        }
    }
}

// K3: block (i,b), 64 threads: s = y[i,:]@W[:,i*32+col] -> squash -> o; z = W@o or final out
__global__ __launch_bounds__(64) void k_out(const float* __restrict__ y, int ybs, int yis,
                                            const float* __restrict__ W, float* __restrict__ z,
                                            float* __restrict__ out, int final){
    __shared__ __align__(16) float ol[DC];
    const int i = blockIdx.x, b = blockIdx.y, t = threadIdx.x;
    const int col = t & 31, half = t >> 5;
    const float* yrow = y + (size_t)b * ybs + i * yis;
    const float* wc = W + i * DC + col;
    float s = 0.f;
    #pragma unroll 4
    for (int dd = 0; dd < 128; dd++){
        int d = half * 128 + dd;
        s += yrow[d] * wc[(size_t)d * 512];
    }
    s += __shfl_xor(s, 32);
    float v = s * s;
    v += __shfl_xor(v, 16); v += __shfl_xor(v, 8); v += __shfl_xor(v, 4);
    v += __shfl_xor(v, 2);  v += __shfl_xor(v, 1);
    float o = s / sqrtf(v + 1e-7f);
    if (final){
        if (t < 32) out[((size_t)b * NC + i) * DC + col] = o;
        return;
    }
    if (t < 32) ol[col] = o;
    __syncthreads();
    float4 ov[8];
    #pragma unroll
    for (int k4 = 0; k4 < 8; k4++) ov[k4] = *(const float4*)&ol[k4 * 4];
    float za[4];
    #pragma unroll
    for (int dd = 0; dd < 4; dd++){
        int d = t * 4 + dd;
        const float4* wr = (const float4*)(W + (size_t)d * 512 + i * DC);
        float acc = 0.f;
        #pragma unroll
        for (int k4 = 0; k4 < 8; k4++){
            float4 wv4 = wr[k4];
            acc += wv4.x * ov[k4].x + wv4.y * ov[k4].y + wv4.z * ov[k4].z + wv4.w * ov[k4].w;
        }
        za[dd] = acc;
    }
    *(float4*)&z[((size_t)b * NC + i) * DIN + t * 4] = make_float4(za[0], za[1], za[2], za[3]);
}

extern "C" void kernel_launch(void* const* d_in, const int* in_sizes, int n_in,
                              void* d_out, int out_size, void* d_ws, size_t ws_size,
                              hipStream_t stream){
    const float* x = (const float*)d_in[0];    // fp32 [128][1024][256]
    const float* W = (const float*)d_in[1];    // fp32 [256][512]
    float* out = (float*)d_out;                // fp32 [128][16][32]
    float* f = (float*)d_ws;
    float* ysum = f;                           // 128*256
    float* y    = f + 32768;                   // 128*16*256
    float* z    = f + 32768 + 524288;          // 128*16*256   (ws total ~4.3 MB)

    // iteration 0: c uniform -> y = colsum(x) (scale-invariant); outputs + z
    hipMemsetAsync(ysum, 0, 32768 * sizeof(float), stream);
    k_colsum<<<dim3(8, BATCH), 256, 0, stream>>>(x, ysum);
    k_out<<<dim3(NC, BATCH), 64, 0, stream>>>(ysum, DIN, 0, W, z, out, 0);
    // iterations 1..3
    for (int it = 1; it < 4; it++){
        hipMemsetAsync(y, 0, (size_t)BATCH * NC * DIN * sizeof(float), stream);
        k_route<<<dim3(NCHUNK, BATCH), 256, 0, stream>>>(x, z, y);
        k_out<<<dim3(NC, BATCH), 64, 0, stream>>>(y, NC * DIN, DIN, W, z, out, it == 3 ? 1 : 0);
    }
}

// Round 4
// 330.684 us; speedup vs baseline: 1.5955x; 1.2019x over previous
//
#include <hip/hip_runtime.h>
#include <hip/hip_bf16.h>

typedef unsigned int u32;
typedef float f32x4 __attribute__((ext_vector_type(4)));
typedef __bf16 bf16x8 __attribute__((ext_vector_type(8)));

#define BATCH 128
#define NIN   1024
#define DIN   256
#define NC    16
#define DC    32
#define NCOL  512   // NC*DC

__device__ __forceinline__ float bflo(u32 v){ return __uint_as_float(v << 16); }
__device__ __forceinline__ float bfhi(u32 v){ return __uint_as_float(v & 0xffff0000u); }
__device__ __forceinline__ u32 bfround(u32 ua){ return (ua + 0x7fffu + ((ua >> 16) & 1u)) >> 16; }
__device__ __forceinline__ u32 pack2(float a, float b){
    return (bfround(__float_as_uint(a)) & 0xffffu) | (bfround(__float_as_uint(b)) << 16);
}
__device__ __forceinline__ bf16x8 ldfrag(const u32* p){
    return __builtin_bit_cast(bf16x8, *(const uint4*)p);
}

// K0: Wt[n][k] = bf16(W[k][n]); word = k-pair
__global__ __launch_bounds__(128) void k_wconv(const float* __restrict__ W, u32* __restrict__ Wt){
    int n = blockIdx.x, t = threadIdx.x;
    float a = W[(size_t)(2 * t)     * NCOL + n];
    float b = W[(size_t)(2 * t + 1) * NCOL + n];
    Wt[n * 128 + t] = pack2(a, b);
}

// K1: u_hat[b][i][j][k] = sum_d x[b][j][d] W[d][i*32+k]  (bf16 out, layout i-major, k innermost)
//     + iter-0 y partial: y0[b][n] += sum_j acc (fp32, pre-rounding)
__global__ __launch_bounds__(512, 4) void k_gemm(const float* __restrict__ x, const u32* __restrict__ Wt,
                                                 u32* __restrict__ uhat, float* __restrict__ y0){
    __shared__ __align__(16) u32 sm[16640];   // union: xl = 64x128 u32 (32 KB) / cs = 64x520 bf16 (66.6 KB)
    u32* xl = sm;
    const int t = threadIdx.x;
    const int jb = blockIdx.x, b = blockIdx.y;
    const int lane = t & 63, wv = t >> 6;
    const int l15 = lane & 15, q = lane >> 4;

    // stage x tile 64x256 fp32 -> bf16 pairs (row-swizzled, round-3-verified layout)
    {
        const float4* xg = (const float4*)(x + ((size_t)b * NIN + jb * 64) * DIN);
        #pragma unroll
        for (int m = 0; m < 4; m++){
            int p = t + 512 * m;                   // float4-pair id 0..2047
            float4 a = xg[2 * p], c = xg[2 * p + 1];
            int j = p >> 5, wq = 4 * (p & 31);
            uint4 v;
            v.x = pack2(a.x, a.y); v.y = pack2(a.z, a.w);
            v.z = pack2(c.x, c.y); v.w = pack2(c.z, c.w);
            *(uint4*)&xl[j * 128 + ((wq + 4 * j) & 127)] = v;
        }
    }
    __syncthreads();

    // K-loop: wave wv owns n in [wv*64, wv*64+64), all 64 m rows. K=256 -> 8 ksteps.
    f32x4 acc[4][4];
    #pragma unroll
    for (int mt = 0; mt < 4; mt++)
        #pragma unroll
        for (int nt = 0; nt < 4; nt++) acc[mt][nt] = (f32x4){0.f, 0.f, 0.f, 0.f};
    const int n0w = wv * 64;
    #pragma unroll
    for (int ks = 0; ks < 8; ks++){
        bf16x8 af[4], bfr[4];
        #pragma unroll
        for (int mt = 0; mt < 4; mt++){
            int jr = mt * 16 + l15;
            af[mt] = ldfrag(&xl[jr * 128 + ((ks * 16 + q * 4 + 4 * jr) & 127)]);
        }
        #pragma unroll
        for (int nt = 0; nt < 4; nt++)
            bfr[nt] = ldfrag(&Wt[(size_t)(n0w + nt * 16 + l15) * 128 + ks * 16 + q * 4]);
        #pragma unroll
        for (int mt = 0; mt < 4; mt++)
            #pragma unroll
            for (int nt = 0; nt < 4; nt++)
                acc[mt][nt] = __builtin_amdgcn_mfma_f32_16x16x32_bf16(af[mt], bfr[nt], acc[mt][nt], 0, 0, 0);
    }

    // iter-0 y: sum this block's 64 j rows per column, reduce over q, atomicAdd
    #pragma unroll
    for (int nt = 0; nt < 4; nt++){
        float v = 0.f;
        #pragma unroll
        for (int mt = 0; mt < 4; mt++)
            #pragma unroll
            for (int r = 0; r < 4; r++) v += acc[mt][nt][r];
        v += __shfl_xor(v, 16);
        v += __shfl_xor(v, 32);
        if (lane < 16) atomicAdd(&y0[b * NCOL + n0w + nt * 16 + lane], v);
    }

    __syncthreads();   // xl dead; reuse as C staging
    __hip_bfloat16* cs = (__hip_bfloat16*)sm;   // [64][520]
    #pragma unroll
    for (int mt = 0; mt < 4; mt++)
        #pragma unroll
        for (int nt = 0; nt < 4; nt++)
            #pragma unroll
            for (int r = 0; r < 4; r++)
                cs[(mt * 16 + q * 4 + r) * 520 + n0w + nt * 16 + l15] = __float2bfloat16(acc[mt][nt][r]);
    __syncthreads();

    // coalesced store: 16B chunk id -> (i, j, k8); consecutive threads = consecutive global addrs
    #pragma unroll
    for (int rep = 0; rep < 8; rep++){
        int id = t + 512 * rep;
        int k8 = id & 3, j = (id >> 2) & 63, i = id >> 8;
        uint4 v = *(uint4*)&sm[j * 260 + i * 16 + k8 * 4];
        *(uint4*)&uhat[(((size_t)b * NC + i) * NIN + jb * 64 + j) * 16 + k8 * 4] = v;
    }
}

// K2: per (b, j-chunk of 64): stage u tile; bb[i][j] = o[i,:]·u[i,j,:]; softmax over i; y += c·u
__global__ __launch_bounds__(256) void k_route_u(const u32* __restrict__ uhat, const float* __restrict__ o,
                                                 float* __restrict__ y){
    __shared__ __align__(16) u32 ul[NC * 1028];   // [i][j*16 + kp], i-stride padded (+4 words)
    __shared__ float ol[NCOL];
    __shared__ float bbc[NC * 65];
    const int jc = blockIdx.x, b = blockIdx.y, t = threadIdx.x;

    ol[t] = o[b * NCOL + t];
    ol[t + 256] = o[b * NCOL + t + 256];
    {
        const u32* ub = uhat + (((size_t)b * NC) * NIN + jc * 64) * 16;
        #pragma unroll
        for (int i = 0; i < NC; i++){
            uint4 v = *(const uint4*)&ub[(size_t)i * NIN * 16 + t * 4];
            *(uint4*)&ul[i * 1028 + t * 4] = v;
        }
    }
    __syncthreads();

    // bb: thread (i = t>>4), 4 j's
    {
        int i = t >> 4;
        float o_[32];
        #pragma unroll
        for (int m = 0; m < 8; m++) *(float4*)&o_[m * 4] = *(const float4*)&ol[i * DC + m * 4];
        #pragma unroll
        for (int g = 0; g < 4; g++){
            int j = (t & 15) + 16 * g;
            float acc = 0.f;
            #pragma unroll
            for (int w4 = 0; w4 < 4; w4++){
                uint4 v = *(const uint4*)&ul[i * 1028 + j * 16 + w4 * 4];
                acc += bflo(v.x) * o_[w4*8+0] + bfhi(v.x) * o_[w4*8+1]
                     + bflo(v.y) * o_[w4*8+2] + bfhi(v.y) * o_[w4*8+3]
                     + bflo(v.z) * o_[w4*8+4] + bfhi(v.z) * o_[w4*8+5]
                     + bflo(v.w) * o_[w4*8+6] + bfhi(v.w) * o_[w4*8+7];
            }
            bbc[i * 65 + j] = acc;
        }
    }
    __syncthreads();

    // softmax over i per j
    if (t < 64){
        float m = -1e30f;
        #pragma unroll
        for (int i = 0; i < NC; i++) m = fmaxf(m, bbc[i * 65 + t]);
        float s = 0.f;
        #pragma unroll
        for (int i = 0; i < NC; i++){ float e = __expf(bbc[i * 65 + t] - m); bbc[i * 65 + t] = e; s += e; }
        float inv = 1.f / s;
        #pragma unroll
        for (int i = 0; i < NC; i++) bbc[i * 65 + t] *= inv;
    }
    __syncthreads();

    // y: thread (i = t>>4, kp = t&15) accumulates 2 k's over 64 j's
    {
        int i = t >> 4, kp = t & 15;
        float a0 = 0.f, a1 = 0.f;
        const u32* ur = &ul[i * 1028 + kp];
        const float* cr = &bbc[i * 65];
        #pragma unroll 8
        for (int j = 0; j < 64; j++){
            float c = cr[j];
            u32 v = ur[j * 16];
            a0 += c * bflo(v);
            a1 += c * bfhi(v);
        }
        atomicAdd(&y[b * NCOL + i * DC + 2 * kp],     a0);
        atomicAdd(&y[b * NCOL + i * DC + 2 * kp + 1], a1);
    }
}

// K3: o = y / sqrt(sum_k y^2 + eps); final -> write out
__global__ __launch_bounds__(512) void k_squash(const float* __restrict__ y, float* __restrict__ o,
                                                float* __restrict__ out, int final){
    int b = blockIdx.x, t = threadIdx.x;
    float v = y[b * NCOL + t];
    float s = v * v;
    s += __shfl_xor(s, 1); s += __shfl_xor(s, 2); s += __shfl_xor(s, 4);
    s += __shfl_xor(s, 8); s += __shfl_xor(s, 16);
    float r = v / sqrtf(s + 1e-7f);
    if (final) out[b * NCOL + t] = r;
    else       o[b * NCOL + t] = r;
}

extern "C" void kernel_launch(void* const* d_in, const int* in_sizes, int n_in,
                              void* d_out, int out_size, void* d_ws, size_t ws_size,
                              hipStream_t stream){
    const float* x = (const float*)d_in[0];    // fp32 [128][1024][256]
    const float* W = (const float*)d_in[1];    // fp32 [256][512]
    float* out = (float*)d_out;                // fp32 [128][16][32]
    float* f = (float*)d_ws;
    float* y    = f;                           // 128*512
    float* o    = f + 65536;                   // 128*512
    u32*   Wt   = (u32*)(f + 131072);          // 512*128 words
    u32*   uhat = (u32*)(f + 131072 + 65536);  // 128*16*1024*16 words = 134 MB

    hipMemsetAsync(y, 0, NCOL * BATCH * sizeof(float), stream);
    k_wconv<<<NCOL, 128, 0, stream>>>(W, Wt);
    k_gemm<<<dim3(16, BATCH), 512, 0, stream>>>(x, Wt, uhat, y);
    k_squash<<<BATCH, 512, 0, stream>>>(y, o, out, 0);
    for (int it = 1; it < 4; it++){
        hipMemsetAsync(y, 0, NCOL * BATCH * sizeof(float), stream);
        k_route_u<<<dim3(16, BATCH), 256, 0, stream>>>(uhat, o, y);
        k_squash<<<BATCH, 512, 0, stream>>>(y, o, out, it == 3 ? 1 : 0);
    }
}

// Round 5
// 321.620 us; speedup vs baseline: 1.6405x; 1.0282x over previous
//
#include <hip/hip_runtime.h>
#include <hip/hip_bf16.h>

typedef unsigned int u32;
typedef float f32x4 __attribute__((ext_vector_type(4)));
typedef __bf16 bf16x8 __attribute__((ext_vector_type(8)));

#define BATCH 128
#define NIN   1024
#define DIN   256
#define NC    16
#define DC    32
#define NCOL  512   // NC*DC

__device__ __forceinline__ float bflo(u32 v){ return __uint_as_float(v << 16); }
__device__ __forceinline__ float bfhi(u32 v){ return __uint_as_float(v & 0xffff0000u); }
__device__ __forceinline__ u32 bfround(u32 ua){ return (ua + 0x7fffu + ((ua >> 16) & 1u)) >> 16; }
__device__ __forceinline__ u32 pack2(float a, float b){
    return (bfround(__float_as_uint(a)) & 0xffffu) | (bfround(__float_as_uint(b)) << 16);
}
__device__ __forceinline__ bf16x8 ldfrag(const u32* p){
    return __builtin_bit_cast(bf16x8, *(const uint4*)p);
}

// K0: Wt2 = W in MFMA B-fragment order. uint4 id = (ntile*8 + ks)*64 + lane:
//     lane (l15,q) -> rows n = ntile*16 + l15, words w = ks*16 + q*4 .. +3 (w = k-pair index)
__global__ __launch_bounds__(256) void k_wconv(const float* __restrict__ W, uint4* __restrict__ Wt2){
    int id = blockIdx.x * 256 + threadIdx.x;       // 0..16383
    int l = id & 63, ks = (id >> 6) & 7, ntile = id >> 9;
    int n = ntile * 16 + (l & 15);
    int w0 = ks * 16 + (l >> 4) * 4;
    u32 r[4];
    #pragma unroll
    for (int e = 0; e < 4; e++){
        int w = w0 + e;
        r[e] = pack2(W[(size_t)(2 * w) * NCOL + n], W[(size_t)(2 * w + 1) * NCOL + n]);
    }
    Wt2[id] = make_uint4(r[0], r[1], r[2], r[3]);
}

// K1: u_hat = x@W via MFMA. Output layout: word[((b*16+jb)*512 + n)*32 + jp], n = i*32+k,
//     jp = (j within block)/2. Also iter-0 y0 += column sums (fp32 accs).
__global__ __launch_bounds__(512) void k_gemm(const float* __restrict__ x, const uint4* __restrict__ Wt2,
                                              u32* __restrict__ uhat, float* __restrict__ y0){
    __shared__ __align__(16) u32 xl[64 * 128];   // 32 KB, row-swizzled bf16 pairs
    const int t = threadIdx.x, jb = blockIdx.x, b = blockIdx.y;
    const int lane = t & 63, wv = t >> 6;
    const int l15 = lane & 15, q = lane >> 4;

    // stage x tile 64x256 fp32 -> bf16 pairs (round-3-verified swizzle)
    {
        const float4* xg = (const float4*)(x + ((size_t)b * NIN + jb * 64) * DIN);
        #pragma unroll
        for (int m = 0; m < 4; m++){
            int p = t + 512 * m;                   // float4-pair id 0..2047
            float4 a = xg[2 * p], c = xg[2 * p + 1];
            int j = p >> 5, wq = 4 * (p & 31);
            uint4 v;
            v.x = pack2(a.x, a.y); v.y = pack2(a.z, a.w);
            v.z = pack2(c.x, c.y); v.w = pack2(c.z, c.w);
            *(uint4*)&xl[j * 128 + ((wq + 4 * j) & 127)] = v;
        }
    }
    __syncthreads();

    f32x4 acc[4][4];
    #pragma unroll
    for (int mt = 0; mt < 4; mt++)
        #pragma unroll
        for (int nt = 0; nt < 4; nt++) acc[mt][nt] = (f32x4){0.f, 0.f, 0.f, 0.f};
    #pragma unroll
    for (int ks = 0; ks < 8; ks++){
        bf16x8 af[4], bfr[4];
        #pragma unroll
        for (int mt = 0; mt < 4; mt++){
            int jr = mt * 16 + l15;
            af[mt] = ldfrag(&xl[jr * 128 + ((ks * 16 + q * 4 + 4 * jr) & 127)]);
        }
        #pragma unroll
        for (int nt = 0; nt < 4; nt++)
            bfr[nt] = __builtin_bit_cast(bf16x8, Wt2[(size_t)(((wv * 4 + nt) * 8 + ks) * 64) + lane]);
        #pragma unroll
        for (int mt = 0; mt < 4; mt++)
            #pragma unroll
            for (int nt = 0; nt < 4; nt++)
                acc[mt][nt] = __builtin_amdgcn_mfma_f32_16x16x32_bf16(af[mt], bfr[nt], acc[mt][nt], 0, 0, 0);
    }

    // iter-0 y: column sums over this block's 64 j rows
    #pragma unroll
    for (int nt = 0; nt < 4; nt++){
        float v = 0.f;
        #pragma unroll
        for (int mt = 0; mt < 4; mt++)
            #pragma unroll
            for (int r = 0; r < 4; r++) v += acc[mt][nt][r];
        v += __shfl_xor(v, 16);
        v += __shfl_xor(v, 32);
        if (lane < 16) atomicAdd(&y0[b * NCOL + wv * 64 + nt * 16 + lane], v);
    }

    // direct store: n-row = 128 B; (mt,q) cover 32-B chunks; 4 mt stores fill each line
    u32* ub = uhat + (((size_t)b * NC + jb) * NCOL) * 32;
    #pragma unroll
    for (int nt = 0; nt < 4; nt++){
        int n = wv * 64 + nt * 16 + l15;
        #pragma unroll
        for (int mt = 0; mt < 4; mt++){
            uint2 v;
            v.x = pack2(acc[mt][nt][0], acc[mt][nt][1]);
            v.y = pack2(acc[mt][nt][2], acc[mt][nt][3]);
            *(uint2*)&ub[n * 32 + mt * 8 + q * 2] = v;
        }
    }
}

// rotate swizzle for route LDS: logical (n, jp) -> word n*32 + ((jp + 4*((n+(n>>3))&7)) & 31)
__device__ __forceinline__ int rot8(int n){ return (n + (n >> 3)) & 7; }

// K2: per (b, j-chunk of 64): bb[i][j] = o[i,:]·u[:,j]; softmax over i; y[n] += sum_j c·u
__global__ __launch_bounds__(256) void k_route_u(const u32* __restrict__ uhat, const float* __restrict__ o,
                                                 float* __restrict__ y){
    __shared__ __align__(16) u32 ul[NCOL * 32];   // 64 KB, rotated rows
    __shared__ float ol[NCOL];
    __shared__ float bbc[NC * 68];
    const int jc = blockIdx.x, b = blockIdx.y, t = threadIdx.x;

    ol[t] = o[b * NCOL + t];
    ol[t + 256] = o[b * NCOL + t + 256];
    {
        const uint4* ug = (const uint4*)(uhat + ((size_t)(b * NC + jc)) * NCOL * 32);
        #pragma unroll
        for (int m = 0; m < 16; m++){
            int id = t + 256 * m;
            int n = id >> 3, jq = id & 7;
            ((uint4*)ul)[n * 8 + ((jq + rot8(n)) & 7)] = ug[id];
        }
    }
    __syncthreads();

    // bb: thread (i = t>>4, jq2 = t&15) handles j = 4*jq2 .. +3 over k = 0..31
    {
        int i = t >> 4, jq2 = t & 15;
        float o_[32];
        #pragma unroll
        for (int e = 0; e < 8; e++) *(float4*)&o_[4 * e] = *(const float4*)&ol[i * DC + 4 * e];
        float a0 = 0.f, a1 = 0.f, a2 = 0.f, a3 = 0.f;
        #pragma unroll
        for (int k = 0; k < 32; k++){
            int n = i * DC + k;
            uint2 v = *(const uint2*)&ul[n * 32 + ((2 * jq2 + 4 * rot8(n)) & 31)];
            float ok = o_[k];
            a0 += ok * bflo(v.x); a1 += ok * bfhi(v.x);
            a2 += ok * bflo(v.y); a3 += ok * bfhi(v.y);
        }
        *(float4*)&bbc[i * 68 + 4 * jq2] = make_float4(a0, a1, a2, a3);
    }
    __syncthreads();

    // softmax over i per j
    if (t < 64){
        float m = -1e30f;
        #pragma unroll
        for (int i = 0; i < NC; i++) m = fmaxf(m, bbc[i * 68 + t]);
        float s = 0.f;
        #pragma unroll
        for (int i = 0; i < NC; i++){ float e = __expf(bbc[i * 68 + t] - m); bbc[i * 68 + t] = e; s += e; }
        float inv = 1.f / s;
        #pragma unroll
        for (int i = 0; i < NC; i++) bbc[i * 68 + t] *= inv;
    }
    __syncthreads();

    // y: thread handles n = t and n = t+256; full 64-j dot per n, one atomic per n
    #pragma unroll
    for (int h = 0; h < 2; h++){
        int n = t + 256 * h;
        int i = n >> 5;
        float s = 0.f;
        #pragma unroll
        for (int w4 = 0; w4 < 8; w4++){
            uint4 v = *(const uint4*)&ul[n * 32 + ((4 * w4 + 4 * rot8(n)) & 31)];
            float4 c0 = *(const float4*)&bbc[i * 68 + 8 * w4];
            float4 c1 = *(const float4*)&bbc[i * 68 + 8 * w4 + 4];
            s += c0.x * bflo(v.x) + c0.y * bfhi(v.x) + c0.z * bflo(v.y) + c0.w * bfhi(v.y)
               + c1.x * bflo(v.z) + c1.y * bfhi(v.z) + c1.z * bflo(v.w) + c1.w * bfhi(v.w);
        }
        atomicAdd(&y[b * NCOL + n], s);
    }
}

// K3: o = y / sqrt(sum_k y^2 + eps); final -> write out
__global__ __launch_bounds__(512) void k_squash(const float* __restrict__ y, float* __restrict__ o,
                                                float* __restrict__ out, int final){
    int b = blockIdx.x, t = threadIdx.x;
    float v = y[b * NCOL + t];
    float s = v * v;
    s += __shfl_xor(s, 1); s += __shfl_xor(s, 2); s += __shfl_xor(s, 4);
    s += __shfl_xor(s, 8); s += __shfl_xor(s, 16);
    float r = v / sqrtf(s + 1e-7f);
    if (final) out[b * NCOL + t] = r;
    else       o[b * NCOL + t] = r;
}

extern "C" void kernel_launch(void* const* d_in, const int* in_sizes, int n_in,
                              void* d_out, int out_size, void* d_ws, size_t ws_size,
                              hipStream_t stream){
    const float* x = (const float*)d_in[0];    // fp32 [128][1024][256]
    const float* W = (const float*)d_in[1];    // fp32 [256][512]
    float* out = (float*)d_out;                // fp32 [128][16][32]
    float* f = (float*)d_ws;
    float* y    = f;                           // 128*512 fp32
    float* o    = f + 65536;                   // 128*512 fp32
    uint4* Wt2  = (uint4*)(f + 131072);        // 16384 uint4 = 256 KB
    u32*   uhat = (u32*)(f + 196608);          // 128*16*512*32 words = 134 MB

    hipMemsetAsync(y, 0, NCOL * BATCH * sizeof(float), stream);
    k_wconv<<<64, 256, 0, stream>>>(W, Wt2);
    k_gemm<<<dim3(16, BATCH), 512, 0, stream>>>(x, Wt2, uhat, y);
    k_squash<<<BATCH, 512, 0, stream>>>(y, o, out, 0);
    for (int it = 1; it < 4; it++){
        hipMemsetAsync(y, 0, NCOL * BATCH * sizeof(float), stream);
        k_route_u<<<dim3(16, BATCH), 256, 0, stream>>>(uhat, o, y);
        k_squash<<<BATCH, 512, 0, stream>>>(y, o, out, it == 3 ? 1 : 0);
    }
}